// Round 1
// baseline (1593.474 us; speedup 1.0000x reference)
//
#include <hip/hip_runtime.h>

#define N_NODES 100000
#define N_EDGES 800000
#define F 128          // IN_FEATS == N_HIDDEN
#define C_OUT 64       // N_CLASSES

// ---------------------------------------------------------------------------
// Kernel 1: zero agg (emb region of d_out, reused as scatter accumulator)
// and deg (in d_ws).
// ---------------------------------------------------------------------------
__global__ __launch_bounds__(256) void zero_kernel(float4* __restrict__ agg4,
                                                   float4* __restrict__ deg4) {
    const int i = blockIdx.x * 256 + threadIdx.x;
    const float4 z = make_float4(0.f, 0.f, 0.f, 0.f);
    const int nAgg4 = (N_NODES * F) / 4;   // 3,200,000
    if (i < nAgg4) {
        agg4[i] = z;
    } else {
        const int j = i - nAgg4;
        if (j < N_NODES / 4) deg4[j] = z;  // 25,000
    }
}

// ---------------------------------------------------------------------------
// Kernel 2: edge scatter. 32 lanes per edge, float4 gather of x[src], 4 native
// fp32 atomics into agg[dst]. Lane 0 of each edge group bumps deg[dst].
// 8 edges per 256-thread block -> exactly 100,000 blocks.
// ---------------------------------------------------------------------------
__global__ __launch_bounds__(256) void edge_kernel(const float* __restrict__ x,
                                                   const int* __restrict__ src,
                                                   const int* __restrict__ dst,
                                                   float* __restrict__ agg,
                                                   float* __restrict__ deg) {
    const int tid = threadIdx.x;
    const int e = blockIdx.x * 8 + (tid >> 5);
    const int l = (tid & 31) * 4;
    const int s = src[e];
    const int d = dst[e];
    const float4 v = *(const float4*)(x + (size_t)s * F + l);
    float* a = agg + (size_t)d * F + l;
    unsafeAtomicAdd(a + 0, v.x);
    unsafeAtomicAdd(a + 1, v.y);
    unsafeAtomicAdd(a + 2, v.z);
    unsafeAtomicAdd(a + 3, v.w);
    if ((tid & 31) == 0) unsafeAtomicAdd(deg + d, 1.0f);
}

// ---------------------------------------------------------------------------
// Kernel 3: fused node pipeline for a 64-node tile.
//   h = (agg + x) / (deg + 1)           (staged into LDS Hs[64][132], padded)
//   emb = relu(h @ Wn + bn)             (4 nodes x 8 feats per thread)
//   out = emb @ Wo + bo                 (4 nodes x 4 cols per thread)
// Thread grid 16x16: node rows {r, r+16, r+32, r+48}, feat cols {4c..4c+3}
// and {64+4c..64+4c+3} -> all LDS reads are float4, conflicts <= 2-way.
// ---------------------------------------------------------------------------
__global__ __launch_bounds__(256) void sage_fused(const float* __restrict__ x,
                                                  const float* __restrict__ agg,
                                                  const float* __restrict__ deg,
                                                  const float* __restrict__ Wn,
                                                  const float* __restrict__ bn,
                                                  const float* __restrict__ Wo,
                                                  const float* __restrict__ bo,
                                                  float* __restrict__ out,
                                                  float* __restrict__ emb) {
    __shared__ __align__(16) float Hs[64][132];  // h_neigh tile, then emb tile
    __shared__ __align__(16) float Ws[4096];     // W chunk (16 KB), reused

    const int tid = threadIdx.x;
    const int node0 = blockIdx.x * 64;

    // ---- stage h_neigh tile (reads agg BEFORE this block overwrites it) ----
    for (int idx = tid; idx < 64 * 32; idx += 256) {
        const int m = idx >> 5;
        const int q = idx & 31;
        const int node = node0 + m;
        float4 v = make_float4(0.f, 0.f, 0.f, 0.f);
        if (node < N_NODES) {
            const float4 a = *(const float4*)(agg + (size_t)node * F + 4 * q);
            const float4 b = *(const float4*)(x + (size_t)node * F + 4 * q);
            const float inv = 1.0f / (deg[node] + 1.0f);
            v = make_float4((a.x + b.x) * inv, (a.y + b.y) * inv,
                            (a.z + b.z) * inv, (a.w + b.w) * inv);
        }
        *(float4*)&Hs[m][4 * q] = v;
    }

    const int r = tid >> 4;  // 0..15 node row
    const int c = tid & 15;  // 0..15 feat col

    // ---- GEMM1: emb = relu(h @ Wn + bn) ----
    float acc[4][8];
    {
        const float4 b0 = *(const float4*)(bn + 4 * c);
        const float4 b1 = *(const float4*)(bn + 64 + 4 * c);
#pragma unroll
        for (int i = 0; i < 4; i++) {
            acc[i][0] = b0.x; acc[i][1] = b0.y; acc[i][2] = b0.z; acc[i][3] = b0.w;
            acc[i][4] = b1.x; acc[i][5] = b1.y; acc[i][6] = b1.z; acc[i][7] = b1.w;
        }
    }
    for (int k0 = 0; k0 < F; k0 += 32) {
        __syncthreads();
        for (int idx = tid; idx < 1024; idx += 256)
            ((float4*)Ws)[idx] = ((const float4*)(Wn + (size_t)k0 * F))[idx];
        __syncthreads();
#pragma unroll
        for (int kk = 0; kk < 32; kk += 4) {
            float4 h4[4];
#pragma unroll
            for (int i = 0; i < 4; i++)
                h4[i] = *(const float4*)&Hs[r + 16 * i][k0 + kk];
#pragma unroll
            for (int t = 0; t < 4; t++) {
                const float4 w0 = *(const float4*)&Ws[(kk + t) * F + 4 * c];
                const float4 w1 = *(const float4*)&Ws[(kk + t) * F + 64 + 4 * c];
#pragma unroll
                for (int i = 0; i < 4; i++) {
                    const float h = ((const float*)&h4[i])[t];
                    acc[i][0] += h * w0.x; acc[i][1] += h * w0.y;
                    acc[i][2] += h * w0.z; acc[i][3] += h * w0.w;
                    acc[i][4] += h * w1.x; acc[i][5] += h * w1.y;
                    acc[i][6] += h * w1.z; acc[i][7] += h * w1.w;
                }
            }
        }
    }

    __syncthreads();  // all Hs (h_neigh) reads done; safe to overwrite with emb

    // ---- relu + store emb to global and back into Hs for GEMM2 ----
#pragma unroll
    for (int i = 0; i < 4; i++) {
        const int m = r + 16 * i;
        const float4 e0 = make_float4(fmaxf(acc[i][0], 0.f), fmaxf(acc[i][1], 0.f),
                                      fmaxf(acc[i][2], 0.f), fmaxf(acc[i][3], 0.f));
        const float4 e1 = make_float4(fmaxf(acc[i][4], 0.f), fmaxf(acc[i][5], 0.f),
                                      fmaxf(acc[i][6], 0.f), fmaxf(acc[i][7], 0.f));
        *(float4*)&Hs[m][4 * c] = e0;
        *(float4*)&Hs[m][64 + 4 * c] = e1;
        const int node = node0 + m;
        if (node < N_NODES) {
            *(float4*)(emb + (size_t)node * F + 4 * c) = e0;
            *(float4*)(emb + (size_t)node * F + 64 + 4 * c) = e1;
        }
    }

    // ---- GEMM2: out = emb @ Wo + bo ----
    float acc2[4][4];
    {
        const float4 b2 = *(const float4*)(bo + 4 * c);
#pragma unroll
        for (int i = 0; i < 4; i++) {
            acc2[i][0] = b2.x; acc2[i][1] = b2.y; acc2[i][2] = b2.z; acc2[i][3] = b2.w;
        }
    }
    for (int k0 = 0; k0 < F; k0 += 64) {
        __syncthreads();  // also guards emb writes into Hs on first iteration
        for (int idx = tid; idx < 1024; idx += 256)
            ((float4*)Ws)[idx] = ((const float4*)(Wo + (size_t)k0 * C_OUT))[idx];
        __syncthreads();
#pragma unroll
        for (int kk = 0; kk < 64; kk += 4) {
            float4 e4[4];
#pragma unroll
            for (int i = 0; i < 4; i++)
                e4[i] = *(const float4*)&Hs[r + 16 * i][k0 + kk];
#pragma unroll
            for (int t = 0; t < 4; t++) {
                const float4 w = *(const float4*)&Ws[(kk + t) * C_OUT + 4 * c];
#pragma unroll
                for (int i = 0; i < 4; i++) {
                    const float e = ((const float*)&e4[i])[t];
                    acc2[i][0] += e * w.x; acc2[i][1] += e * w.y;
                    acc2[i][2] += e * w.z; acc2[i][3] += e * w.w;
                }
            }
        }
    }
#pragma unroll
    for (int i = 0; i < 4; i++) {
        const int node = node0 + r + 16 * i;
        if (node < N_NODES) {
            const float4 o = make_float4(acc2[i][0], acc2[i][1], acc2[i][2], acc2[i][3]);
            *(float4*)(out + (size_t)node * C_OUT + 4 * c) = o;
        }
    }
}

extern "C" void kernel_launch(void* const* d_in, const int* in_sizes, int n_in,
                              void* d_out, int out_size, void* d_ws, size_t ws_size,
                              hipStream_t stream) {
    const float* x  = (const float*)d_in[0];
    const int* src  = (const int*)d_in[1];
    const int* dst  = (const int*)d_in[2];
    const float* Wn = (const float*)d_in[3];
    const float* bn = (const float*)d_in[4];
    const float* Wo = (const float*)d_in[5];
    const float* bo = (const float*)d_in[6];

    float* out = (float*)d_out;                      // [N_NODES, 64]
    float* emb = out + (size_t)N_NODES * C_OUT;      // [N_NODES, 128]
    float* agg = emb;   // scatter accumulator aliases the emb output region
    float* deg = (float*)d_ws;                       // [N_NODES]

    // zero agg (3.2M float4) + deg (25k float4)
    const int nZero4 = (N_NODES * F) / 4 + N_NODES / 4;  // 3,225,000
    zero_kernel<<<(nZero4 + 255) / 256, 256, 0, stream>>>((float4*)agg, (float4*)deg);

    // scatter-add x[src] into agg[dst], count deg
    edge_kernel<<<N_EDGES / 8, 256, 0, stream>>>(x, src, dst, agg, deg);

    // fused: h_neigh -> GEMM1 -> relu -> emb -> GEMM2 -> out
    sage_fused<<<(N_NODES + 63) / 64, 256, 0, stream>>>(x, agg, deg, Wn, bn, Wo, bo,
                                                        out, emb);
}

// Round 2
// 321.167 us; speedup vs baseline: 4.9615x; 4.9615x over previous
//
#include <hip/hip_runtime.h>

#define N_NODES 100000
#define N_EDGES 800000
#define F 128          // IN_FEATS == N_HIDDEN
#define C_OUT 64       // N_CLASSES
#define CAP 48         // per-node edge bucket capacity (Poisson(8): P(deg>=48)~1e-25)

// ---------------------------------------------------------------------------
// Kernel 1: bucket fill. One thread per edge: slot = cnt[dst]++ (int atomic),
// bucket[dst*CAP + slot] = src.  800k int atomics vs 102.4M fp32 before.
// ---------------------------------------------------------------------------
__global__ __launch_bounds__(256) void fill_kernel(const int* __restrict__ src,
                                                   const int* __restrict__ dst,
                                                   int* __restrict__ bucket,
                                                   int* __restrict__ cnt) {
    const int e = blockIdx.x * 256 + threadIdx.x;
    if (e >= N_EDGES) return;
    const int d = dst[e];
    const int slot = atomicAdd(cnt + d, 1);
    if (slot < CAP) bucket[(size_t)d * CAP + slot] = src[e];
}

// ---------------------------------------------------------------------------
// Kernel 2: gather + normalize. One 64-lane wave per node; lane holds float2
// (64 x 8B = 512B = one x row, fully coalesced per in-edge).
//   h[v] = (sum_{u->v} x[u] + x[v]) / (deg(v) + 1)
// ---------------------------------------------------------------------------
__global__ __launch_bounds__(256) void gather_kernel(const float* __restrict__ x,
                                                     const int* __restrict__ bucket,
                                                     const int* __restrict__ cnt,
                                                     float* __restrict__ h) {
    const int node = blockIdx.x * 4 + (threadIdx.x >> 6);
    if (node >= N_NODES) return;
    const int lane = threadIdx.x & 63;
    const int deg = cnt[node];
    const int n = deg < CAP ? deg : CAP;

    float2 acc = ((const float2*)(x + (size_t)node * F))[lane];  // self term
    const int* bk = bucket + (size_t)node * CAP;
    int i = 0;
    // 4-wide software pipeline: 4 independent row loads in flight
    for (; i + 4 <= n; i += 4) {
        const int s0 = bk[i], s1 = bk[i + 1], s2 = bk[i + 2], s3 = bk[i + 3];
        const float2 v0 = ((const float2*)(x + (size_t)s0 * F))[lane];
        const float2 v1 = ((const float2*)(x + (size_t)s1 * F))[lane];
        const float2 v2 = ((const float2*)(x + (size_t)s2 * F))[lane];
        const float2 v3 = ((const float2*)(x + (size_t)s3 * F))[lane];
        acc.x += v0.x + v1.x + v2.x + v3.x;
        acc.y += v0.y + v1.y + v2.y + v3.y;
    }
    for (; i < n; i++) {
        const float2 v = ((const float2*)(x + (size_t)bk[i] * F))[lane];
        acc.x += v.x;
        acc.y += v.y;
    }
    const float inv = 1.0f / (float)(deg + 1);
    acc.x *= inv;
    acc.y *= inv;
    ((float2*)(h + (size_t)node * F))[lane] = acc;
}

// ---------------------------------------------------------------------------
// Kernel 3: fused node pipeline for a 64-node tile.
//   emb = relu(h @ Wn + bn)             (4 nodes x 8 feats per thread)
//   out = emb @ Wo + bo                 (4 nodes x 4 cols per thread)
// h aliases the emb output region; each block reads its own 64 rows before
// overwriting them (barrier-protected, block-local).
// ---------------------------------------------------------------------------
__global__ __launch_bounds__(256) void sage_fused(const float* __restrict__ h,
                                                  const float* __restrict__ Wn,
                                                  const float* __restrict__ bn,
                                                  const float* __restrict__ Wo,
                                                  const float* __restrict__ bo,
                                                  float* __restrict__ out,
                                                  float* __restrict__ emb) {
    __shared__ __align__(16) float Hs[64][132];  // h tile, then emb tile
    __shared__ __align__(16) float Ws[4096];     // W chunk (16 KB), reused

    const int tid = threadIdx.x;
    const int node0 = blockIdx.x * 64;

    // ---- stage h tile ----
    for (int idx = tid; idx < 64 * 32; idx += 256) {
        const int m = idx >> 5;
        const int q = idx & 31;
        const int node = node0 + m;
        float4 v = make_float4(0.f, 0.f, 0.f, 0.f);
        if (node < N_NODES) v = *(const float4*)(h + (size_t)node * F + 4 * q);
        *(float4*)&Hs[m][4 * q] = v;
    }

    const int r = tid >> 4;  // 0..15 node row
    const int c = tid & 15;  // 0..15 feat col

    // ---- GEMM1: emb = relu(h @ Wn + bn) ----
    float acc[4][8];
    {
        const float4 b0 = *(const float4*)(bn + 4 * c);
        const float4 b1 = *(const float4*)(bn + 64 + 4 * c);
#pragma unroll
        for (int i = 0; i < 4; i++) {
            acc[i][0] = b0.x; acc[i][1] = b0.y; acc[i][2] = b0.z; acc[i][3] = b0.w;
            acc[i][4] = b1.x; acc[i][5] = b1.y; acc[i][6] = b1.z; acc[i][7] = b1.w;
        }
    }
    for (int k0 = 0; k0 < F; k0 += 32) {
        __syncthreads();
        for (int idx = tid; idx < 1024; idx += 256)
            ((float4*)Ws)[idx] = ((const float4*)(Wn + (size_t)k0 * F))[idx];
        __syncthreads();
#pragma unroll
        for (int kk = 0; kk < 32; kk += 4) {
            float4 h4[4];
#pragma unroll
            for (int i = 0; i < 4; i++)
                h4[i] = *(const float4*)&Hs[r + 16 * i][k0 + kk];
#pragma unroll
            for (int t = 0; t < 4; t++) {
                const float4 w0 = *(const float4*)&Ws[(kk + t) * F + 4 * c];
                const float4 w1 = *(const float4*)&Ws[(kk + t) * F + 64 + 4 * c];
#pragma unroll
                for (int i = 0; i < 4; i++) {
                    const float hv = ((const float*)&h4[i])[t];
                    acc[i][0] += hv * w0.x; acc[i][1] += hv * w0.y;
                    acc[i][2] += hv * w0.z; acc[i][3] += hv * w0.w;
                    acc[i][4] += hv * w1.x; acc[i][5] += hv * w1.y;
                    acc[i][6] += hv * w1.z; acc[i][7] += hv * w1.w;
                }
            }
        }
    }

    __syncthreads();  // all Hs (h) reads done; safe to overwrite with emb

    // ---- relu + store emb to global and back into Hs for GEMM2 ----
#pragma unroll
    for (int i = 0; i < 4; i++) {
        const int m = r + 16 * i;
        const float4 e0 = make_float4(fmaxf(acc[i][0], 0.f), fmaxf(acc[i][1], 0.f),
                                      fmaxf(acc[i][2], 0.f), fmaxf(acc[i][3], 0.f));
        const float4 e1 = make_float4(fmaxf(acc[i][4], 0.f), fmaxf(acc[i][5], 0.f),
                                      fmaxf(acc[i][6], 0.f), fmaxf(acc[i][7], 0.f));
        *(float4*)&Hs[m][4 * c] = e0;
        *(float4*)&Hs[m][64 + 4 * c] = e1;
        const int node = node0 + m;
        if (node < N_NODES) {
            *(float4*)(emb + (size_t)node * F + 4 * c) = e0;
            *(float4*)(emb + (size_t)node * F + 64 + 4 * c) = e1;
        }
    }

    // ---- GEMM2: out = emb @ Wo + bo ----
    float acc2[4][4];
    {
        const float4 b2 = *(const float4*)(bo + 4 * c);
#pragma unroll
        for (int i = 0; i < 4; i++) {
            acc2[i][0] = b2.x; acc2[i][1] = b2.y; acc2[i][2] = b2.z; acc2[i][3] = b2.w;
        }
    }
    for (int k0 = 0; k0 < F; k0 += 64) {
        __syncthreads();  // also guards emb writes into Hs on first iteration
        for (int idx = tid; idx < 1024; idx += 256)
            ((float4*)Ws)[idx] = ((const float4*)(Wo + (size_t)k0 * C_OUT))[idx];
        __syncthreads();
#pragma unroll
        for (int kk = 0; kk < 64; kk += 4) {
            float4 e4[4];
#pragma unroll
            for (int i = 0; i < 4; i++)
                e4[i] = *(const float4*)&Hs[r + 16 * i][k0 + kk];
#pragma unroll
            for (int t = 0; t < 4; t++) {
                const float4 w = *(const float4*)&Ws[(kk + t) * C_OUT + 4 * c];
#pragma unroll
                for (int i = 0; i < 4; i++) {
                    const float ev = ((const float*)&e4[i])[t];
                    acc2[i][0] += ev * w.x; acc2[i][1] += ev * w.y;
                    acc2[i][2] += ev * w.z; acc2[i][3] += ev * w.w;
                }
            }
        }
    }
#pragma unroll
    for (int i = 0; i < 4; i++) {
        const int node = node0 + r + 16 * i;
        if (node < N_NODES) {
            const float4 o = make_float4(acc2[i][0], acc2[i][1], acc2[i][2], acc2[i][3]);
            *(float4*)(out + (size_t)node * C_OUT + 4 * c) = o;
        }
    }
}

extern "C" void kernel_launch(void* const* d_in, const int* in_sizes, int n_in,
                              void* d_out, int out_size, void* d_ws, size_t ws_size,
                              hipStream_t stream) {
    const float* x  = (const float*)d_in[0];
    const int* src  = (const int*)d_in[1];
    const int* dst  = (const int*)d_in[2];
    const float* Wn = (const float*)d_in[3];
    const float* bn = (const float*)d_in[4];
    const float* Wo = (const float*)d_in[5];
    const float* bo = (const float*)d_in[6];

    float* out = (float*)d_out;                      // [N_NODES, 64]
    float* emb = out + (size_t)N_NODES * C_OUT;      // [N_NODES, 128]
    float* h   = emb;        // h_neigh buffer aliases the emb output region
    int* bucket = (int*)d_out;   // 100k*48 ints = 19.2 MB, aliases `out` region
                                 // (out is written only at the very end of
                                 //  sage_fused, after gather completed)
    int* cnt = (int*)d_ws;       // [N_NODES] in-degree counters

    // zero the degree counters (400 KB)
    hipMemsetAsync(cnt, 0, N_NODES * sizeof(int), stream);

    // bucket edges by destination: one int atomic per edge
    fill_kernel<<<(N_EDGES + 255) / 256, 256, 0, stream>>>(src, dst, bucket, cnt);

    // gather + normalize: h = (sum_{u->v} x[u] + x[v]) / (deg+1)
    gather_kernel<<<(N_NODES + 3) / 4, 256, 0, stream>>>(x, bucket, cnt, h);

    // fused: GEMM1 -> relu -> emb -> GEMM2 -> out
    sage_fused<<<(N_NODES + 63) / 64, 256, 0, stream>>>(h, Wn, bn, Wo, bo, out, emb);
}

// Round 3
// 276.543 us; speedup vs baseline: 5.7621x; 1.1614x over previous
//
#include <hip/hip_runtime.h>
#include <hip/hip_bf16.h>

#define N_NODES 100000
#define N_EDGES 800000
#define F 128          // IN_FEATS == N_HIDDEN
#define C_OUT 64       // N_CLASSES
#define CAP 48         // per-node bucket capacity (Poisson(8): P(deg>=48)~1e-25)

typedef __bf16 bf16x8 __attribute__((ext_vector_type(8)));
typedef __bf16 bf16x2 __attribute__((ext_vector_type(2)));
typedef float f32x4 __attribute__((ext_vector_type(4)));

// ---------------------------------------------------------------------------
// Kernel 1: bucket fill. slot = cnt[dst]++ ; bucket for node v lives in the
// first 48 ints of v's own emb row (emb row = 512 B, written only by v's own
// wave AFTER it has consumed the bucket -> no cross-block race).
// ---------------------------------------------------------------------------
__global__ __launch_bounds__(256) void fill_kernel(const int* __restrict__ src,
                                                   const int* __restrict__ dst,
                                                   float* __restrict__ emb,
                                                   int* __restrict__ cnt) {
    const int e = blockIdx.x * 256 + threadIdx.x;
    if (e >= N_EDGES) return;
    const int d = dst[e];
    const int slot = atomicAdd(cnt + d, 1);
    if (slot < CAP) ((int*)(emb + (size_t)d * F))[slot] = src[e];
}

// ---------------------------------------------------------------------------
// Kernel 2: weight swizzle -> bf16 B-fragment-linear layout in d_ws.
// B-frag (mfma_f32_16x16x32_bf16): lane l holds B[k=(l>>4)*8+j][n=(l&15)].
// Group g = (nb*4+kb)*64 + lane; Ws[g*8 + j].
// t in [0,2048): Wn (128x128). t in [2048,3072): Wo (128x64).
// ---------------------------------------------------------------------------
__global__ __launch_bounds__(256) void swizzle_kernel(const float* __restrict__ Wn,
                                                      const float* __restrict__ Wo,
                                                      __bf16* __restrict__ Wn_s,
                                                      __bf16* __restrict__ Wo_s) {
    const int t = blockIdx.x * 256 + threadIdx.x;
    const float* W;
    __bf16* Ws;
    int g, ncols;
    if (t < 2048) { W = Wn; Ws = Wn_s; g = t;        ncols = 128; }
    else          { W = Wo; Ws = Wo_s; g = t - 2048; ncols = 64;  }
    const int l = g & 63;
    const int kb = (g >> 6) & 3;
    const int nb = g >> 8;
    const int q = l >> 4, m = l & 15;
    const int n = nb * 16 + m;
    __bf16 v[8];
#pragma unroll
    for (int j = 0; j < 8; j++) {
        const int k = kb * 32 + q * 8 + j;
        v[j] = (__bf16)W[(size_t)k * ncols + n];
    }
    *(bf16x8*)(Ws + (size_t)g * 8) = *(bf16x8*)v;
}

// ---------------------------------------------------------------------------
// Kernel 3: fully fused, wave-local. Wave w of each 64-node block:
//   gather 16 nodes -> h bf16 in LDS rows [w*16, w*16+16)
//   GEMM1 (MFMA): emb = relu(h @ Wn + bn)  -> global fp32 + LDS bf16 (same rows)
//   GEMM2 (MFMA): out = emb @ Wo + bo      -> global fp32
// A-frag: lane holds A[m=lane&15][k=(lane>>4)*8+j]; C/D: row=(lane>>4)*4+r,
// col=lane&15 (m89/m120-verified layouts).
// ---------------------------------------------------------------------------
__global__ __launch_bounds__(256) void sage_mfma(const float* __restrict__ x,
                                                 const int* __restrict__ cnt,
                                                 const __bf16* __restrict__ Wn_s,
                                                 const __bf16* __restrict__ Wo_s,
                                                 const float* __restrict__ bn,
                                                 const float* __restrict__ bo,
                                                 float* __restrict__ out,
                                                 float* __restrict__ emb) {
    __shared__ __align__(16) __bf16 Hs[64][136];  // row stride 272 B (17*16)

    const int tid = threadIdx.x;
    const int w = tid >> 6;
    const int lane = tid & 63;
    const int node0 = blockIdx.x * 64;
    const int q = lane >> 4, m = lane & 15;

    // ---- gather: h[v] = (sum_{u->v} x[u] + x[v]) / (deg+1), bf16 into LDS ----
    for (int i = 0; i < 16; i++) {
        const int row = w * 16 + i;
        const int node = node0 + row;
        float2 acc = make_float2(0.f, 0.f);
        if (node < N_NODES) {
            const int deg = cnt[node];
            const int n = deg < CAP ? deg : CAP;
            acc = ((const float2*)(x + (size_t)node * F))[lane];  // self term
            const int* bk = (const int*)(emb + (size_t)node * F); // bucket in emb row
            int j = 0;
            for (; j + 4 <= n; j += 4) {
                const int4 s4 = *(const int4*)(bk + j);
                const float2 v0 = ((const float2*)(x + (size_t)s4.x * F))[lane];
                const float2 v1 = ((const float2*)(x + (size_t)s4.y * F))[lane];
                const float2 v2 = ((const float2*)(x + (size_t)s4.z * F))[lane];
                const float2 v3 = ((const float2*)(x + (size_t)s4.w * F))[lane];
                acc.x += v0.x + v1.x + v2.x + v3.x;
                acc.y += v0.y + v1.y + v2.y + v3.y;
            }
            for (; j < n; j++) {
                const float2 v = ((const float2*)(x + (size_t)bk[j] * F))[lane];
                acc.x += v.x;
                acc.y += v.y;
            }
            const float inv = 1.0f / (float)(deg + 1);
            acc.x *= inv;
            acc.y *= inv;
        }
        bf16x2 h2;
        h2.x = (__bf16)acc.x;
        h2.y = (__bf16)acc.y;
        *(bf16x2*)&Hs[row][2 * lane] = h2;  // 4B store, conflict-free
    }

    // ---- GEMM1: emb = relu(h @ Wn + bn), 16x128 per wave via MFMA ----
    bf16x8 a[4];
#pragma unroll
    for (int kb = 0; kb < 4; kb++)
        a[kb] = *(const bf16x8*)&Hs[w * 16 + m][kb * 32 + q * 8];

    f32x4 acc1[8];
#pragma unroll
    for (int nb = 0; nb < 8; nb++) {
        f32x4 c = {0.f, 0.f, 0.f, 0.f};
#pragma unroll
        for (int kb = 0; kb < 4; kb++) {
            const bf16x8 b = *(const bf16x8*)(Wn_s + ((size_t)(nb * 4 + kb) * 64 + lane) * 8);
            c = __builtin_amdgcn_mfma_f32_16x16x32_bf16(a[kb], b, c, 0, 0, 0);
        }
        acc1[nb] = c;
    }

    // ---- epilogue 1: bias + relu; emb -> global fp32 AND back into Hs bf16 ----
#pragma unroll
    for (int nb = 0; nb < 8; nb++) {
        const int col = nb * 16 + m;
        const float bias = bn[col];
#pragma unroll
        for (int r = 0; r < 4; r++) {
            const int row = w * 16 + q * 4 + r;
            const float e = fmaxf(acc1[nb][r] + bias, 0.f);
            Hs[row][col] = (__bf16)e;
            const int node = node0 + row;
            if (node < N_NODES) emb[(size_t)node * F + col] = e;
        }
    }

    __syncthreads();  // defensive fence (all LDS traffic is wave-local)

    // ---- GEMM2: out = emb @ Wo + bo ----
    bf16x8 a2[4];
#pragma unroll
    for (int kb = 0; kb < 4; kb++)
        a2[kb] = *(const bf16x8*)&Hs[w * 16 + m][kb * 32 + q * 8];

#pragma unroll
    for (int nb = 0; nb < 4; nb++) {
        f32x4 c = {0.f, 0.f, 0.f, 0.f};
#pragma unroll
        for (int kb = 0; kb < 4; kb++) {
            const bf16x8 b = *(const bf16x8*)(Wo_s + ((size_t)(nb * 4 + kb) * 64 + lane) * 8);
            c = __builtin_amdgcn_mfma_f32_16x16x32_bf16(a2[kb], b, c, 0, 0, 0);
        }
        const int col = nb * 16 + m;
        const float bias = bo[col];
#pragma unroll
        for (int r = 0; r < 4; r++) {
            const int node = node0 + w * 16 + q * 4 + r;
            if (node < N_NODES) out[(size_t)node * C_OUT + col] = c[r] + bias;
        }
    }
}

extern "C" void kernel_launch(void* const* d_in, const int* in_sizes, int n_in,
                              void* d_out, int out_size, void* d_ws, size_t ws_size,
                              hipStream_t stream) {
    const float* x  = (const float*)d_in[0];
    const int* src  = (const int*)d_in[1];
    const int* dst  = (const int*)d_in[2];
    const float* Wn = (const float*)d_in[3];
    const float* bn = (const float*)d_in[4];
    const float* Wo = (const float*)d_in[5];
    const float* bo = (const float*)d_in[6];

    float* out = (float*)d_out;                  // [N_NODES, 64]
    float* emb = out + (size_t)N_NODES * C_OUT;  // [N_NODES, 128]

    int* cnt = (int*)d_ws;                                   // 400 KB
    __bf16* Wn_s = (__bf16*)((char*)d_ws + 400000);          // 32 KB (16B-aligned)
    __bf16* Wo_s = Wn_s + 128 * 128;                         // 16 KB

    hipMemsetAsync(cnt, 0, N_NODES * sizeof(int), stream);

    // bucket edges by destination (bucket lives inside each node's emb row)
    fill_kernel<<<(N_EDGES + 255) / 256, 256, 0, stream>>>(src, dst, emb, cnt);

    // weights -> bf16 B-fragment layout
    swizzle_kernel<<<12, 256, 0, stream>>>(Wn, Wo, Wn_s, Wo_s);

    // fused gather + GEMM1 + relu + GEMM2
    sage_mfma<<<(N_NODES + 63) / 64, 256, 0, stream>>>(x, cnt, Wn_s, Wo_s, bn, bo,
                                                       out, emb);
}

// Round 4
// 248.771 us; speedup vs baseline: 6.4054x; 1.1116x over previous
//
#include <hip/hip_runtime.h>
#include <hip/hip_bf16.h>

#define N_NODES 100000
#define N_EDGES 800000
#define F 128          // IN_FEATS == N_HIDDEN
#define C_OUT 64       // N_CLASSES
#define CAP 48         // per-node bucket capacity (Poisson(8): P(deg>=48)~1e-25)

typedef __bf16 bf16x8 __attribute__((ext_vector_type(8)));
typedef __bf16 bf16x4 __attribute__((ext_vector_type(4)));
typedef __bf16 bf16x2 __attribute__((ext_vector_type(2)));
typedef float f32x4 __attribute__((ext_vector_type(4)));

// ---------------------------------------------------------------------------
// Kernel 1: x fp32 -> xb bf16 (xb lives in the `out` region of d_out: exactly
// 100k*128 bf16 = 25.6 MB). Also zeroes the degree counters.
// 800,000 threads, one float4 -> bf16x4 each. Grid 3125*256 exact.
// ---------------------------------------------------------------------------
__global__ __launch_bounds__(256) void conv_zero(const float* __restrict__ x,
                                                 __bf16* __restrict__ xb,
                                                 int4* __restrict__ cnt4) {
    const int i = blockIdx.x * 256 + threadIdx.x;
    const float4 v = ((const float4*)x)[i];
    bf16x4 b;
    b.x = (__bf16)v.x; b.y = (__bf16)v.y; b.z = (__bf16)v.z; b.w = (__bf16)v.w;
    *(bf16x4*)(xb + (size_t)i * 4) = b;
    if (i < N_NODES / 4) cnt4[i] = make_int4(0, 0, 0, 0);
}

// ---------------------------------------------------------------------------
// Kernel 2: bucket fill. slot = cnt[dst]++ ; bucket for node v = first 48 ints
// of v's emb row (row-local: only v's wave reads it, then overwrites with emb).
// ---------------------------------------------------------------------------
__global__ __launch_bounds__(256) void fill_kernel(const int* __restrict__ src,
                                                   const int* __restrict__ dst,
                                                   float* __restrict__ emb,
                                                   int* __restrict__ cnt) {
    const int e = blockIdx.x * 256 + threadIdx.x;
    if (e >= N_EDGES) return;
    const int d = dst[e];
    const int slot = atomicAdd(cnt + d, 1);
    if (slot < CAP) ((int*)(emb + (size_t)d * F))[slot] = src[e];
}

// ---------------------------------------------------------------------------
// Kernel 3: weight swizzle -> bf16 B-fragment-linear layout in d_ws.
// B-frag (mfma_f32_16x16x32_bf16): lane l holds B[k=(l>>4)*8+j][n=(l&15)].
// Group g = (nb*4+kb)*64 + lane; Ws[g*8 + j]. (validated in R3)
// ---------------------------------------------------------------------------
__global__ __launch_bounds__(256) void swizzle_kernel(const float* __restrict__ Wn,
                                                      const float* __restrict__ Wo,
                                                      __bf16* __restrict__ Wn_s,
                                                      __bf16* __restrict__ Wo_s) {
    const int t = blockIdx.x * 256 + threadIdx.x;
    const float* W;
    __bf16* Ws;
    int g, ncols;
    if (t < 2048) { W = Wn; Ws = Wn_s; g = t;        ncols = 128; }
    else          { W = Wo; Ws = Wo_s; g = t - 2048; ncols = 64;  }
    const int l = g & 63;
    const int kb = (g >> 6) & 3;
    const int nb = g >> 8;
    const int q = l >> 4, m = l & 15;
    const int n = nb * 16 + m;
    __bf16 v[8];
#pragma unroll
    for (int j = 0; j < 8; j++) {
        const int k = kb * 32 + q * 8 + j;
        v[j] = (__bf16)W[(size_t)k * ncols + n];
    }
    *(bf16x8*)(Ws + (size_t)g * 8) = *(bf16x8*)v;
}

// 4-edge gather step: bucket int4 -> 4 bf16 row loads (4 B/lane, 256 B/row)
#define ACC4(bk, j, acc)                                                      \
    {                                                                         \
        const int4 s4 = *(const int4*)((bk) + (j));                           \
        const bf16x2 v0 = *(const bf16x2*)(xb + (size_t)s4.x * F + 2 * lane); \
        const bf16x2 v1 = *(const bf16x2*)(xb + (size_t)s4.y * F + 2 * lane); \
        const bf16x2 v2 = *(const bf16x2*)(xb + (size_t)s4.z * F + 2 * lane); \
        const bf16x2 v3 = *(const bf16x2*)(xb + (size_t)s4.w * F + 2 * lane); \
        acc.x += (float)v0.x + (float)v1.x + (float)v2.x + (float)v3.x;       \
        acc.y += (float)v0.y + (float)v1.y + (float)v2.y + (float)v3.y;       \
    }

#define ACC1(bk, j, acc)                                                       \
    {                                                                          \
        const int s = (bk)[j];                                                 \
        const bf16x2 v = *(const bf16x2*)(xb + (size_t)s * F + 2 * lane);      \
        acc.x += (float)v.x;                                                   \
        acc.y += (float)v.y;                                                   \
    }

// ---------------------------------------------------------------------------
// Kernel 4: one wave per 16 nodes (6250 blocks, wave-local, no barriers).
//   gather (bf16 rows, 2 nodes interleaved for 8 loads in flight)
//   -> h bf16 in LDS -> MFMA GEMM1 -> relu -> emb (fp32, global).
// A-frag: lane holds A[m=lane&15][k=(lane>>4)*8+j]; C/D: row=(lane>>4)*4+r,
// col=lane&15.
// ---------------------------------------------------------------------------
__global__ __launch_bounds__(64) void sage1(const __bf16* __restrict__ xb,
                                            const int* __restrict__ cnt,
                                            const __bf16* __restrict__ Wn_s,
                                            const float* __restrict__ bn,
                                            float* emb) {
    __shared__ __align__(16) __bf16 Hs[16][136];  // row stride 272 B
    const int lane = threadIdx.x;
    const int node0 = blockIdx.x * 16;  // 100000 = 6250*16 exact, no guards
    const int q = lane >> 4, m = lane & 15;

    // ---- gather: h[v] = (sum_{u->v} xb[u] + xb[v]) / (deg+1) ----
    for (int i = 0; i < 16; i += 2) {
        const int nodeA = node0 + i, nodeB = nodeA + 1;
        const int degA = cnt[nodeA], degB = cnt[nodeB];
        const int nA = degA < CAP ? degA : CAP;
        const int nB = degB < CAP ? degB : CAP;
        const bf16x2 sA = *(const bf16x2*)(xb + (size_t)nodeA * F + 2 * lane);
        const bf16x2 sB = *(const bf16x2*)(xb + (size_t)nodeB * F + 2 * lane);
        float2 accA = make_float2((float)sA.x, (float)sA.y);
        float2 accB = make_float2((float)sB.x, (float)sB.y);
        const int* bkA = (const int*)(emb + (size_t)nodeA * F);
        const int* bkB = (const int*)(emb + (size_t)nodeB * F);
        int ja = 0, jb = 0;
        while ((ja + 4 <= nA) && (jb + 4 <= nB)) {  // 8 row loads in flight
            ACC4(bkA, ja, accA);
            ACC4(bkB, jb, accB);
            ja += 4; jb += 4;
        }
        while (ja + 4 <= nA) { ACC4(bkA, ja, accA); ja += 4; }
        while (jb + 4 <= nB) { ACC4(bkB, jb, accB); jb += 4; }
        while ((ja < nA) && (jb < nB)) { ACC1(bkA, ja, accA); ACC1(bkB, jb, accB); ja++; jb++; }
        while (ja < nA) { ACC1(bkA, ja, accA); ja++; }
        while (jb < nB) { ACC1(bkB, jb, accB); jb++; }

        const float invA = 1.0f / (float)(degA + 1);
        const float invB = 1.0f / (float)(degB + 1);
        bf16x2 hA, hB;
        hA.x = (__bf16)(accA.x * invA); hA.y = (__bf16)(accA.y * invA);
        hB.x = (__bf16)(accB.x * invB); hB.y = (__bf16)(accB.y * invB);
        *(bf16x2*)&Hs[i][2 * lane] = hA;
        *(bf16x2*)&Hs[i + 1][2 * lane] = hB;
    }

    // ---- GEMM1: emb = relu(h @ Wn + bn), 16x128 via MFMA ----
    bf16x8 a[4];
#pragma unroll
    for (int kb = 0; kb < 4; kb++)
        a[kb] = *(const bf16x8*)&Hs[m][kb * 32 + q * 8];

#pragma unroll
    for (int nb = 0; nb < 8; nb++) {
        f32x4 c = {0.f, 0.f, 0.f, 0.f};
#pragma unroll
        for (int kb = 0; kb < 4; kb++) {
            const bf16x8 b = *(const bf16x8*)(Wn_s + ((size_t)(nb * 4 + kb) * 64 + lane) * 8);
            c = __builtin_amdgcn_mfma_f32_16x16x32_bf16(a[kb], b, c, 0, 0, 0);
        }
        const int col = nb * 16 + m;
        const float bias = bn[col];
#pragma unroll
        for (int r = 0; r < 4; r++) {
            const int row = q * 4 + r;
            emb[(size_t)(node0 + row) * F + col] = fmaxf(c[r] + bias, 0.f);
        }
    }
}

// ---------------------------------------------------------------------------
// Kernel 5: out = emb @ Wo + bo. One wave per 16 nodes, A-frags straight from
// global emb (fp32 -> bf16 in-register). Runs after sage1, so xb (out region)
// is dead and can be overwritten.
// ---------------------------------------------------------------------------
__global__ __launch_bounds__(64) void sage2(const float* __restrict__ emb,
                                            const __bf16* __restrict__ Wo_s,
                                            const float* __restrict__ bo,
                                            float* __restrict__ out) {
    const int lane = threadIdx.x;
    const int node0 = blockIdx.x * 16;
    const int q = lane >> 4, m = lane & 15;

    bf16x8 a[4];
#pragma unroll
    for (int kb = 0; kb < 4; kb++) {
        const float* p = emb + (size_t)(node0 + m) * F + kb * 32 + q * 8;
        const float4 f0 = *(const float4*)(p);
        const float4 f1 = *(const float4*)(p + 4);
        bf16x8 v;
        v[0] = (__bf16)f0.x; v[1] = (__bf16)f0.y; v[2] = (__bf16)f0.z; v[3] = (__bf16)f0.w;
        v[4] = (__bf16)f1.x; v[5] = (__bf16)f1.y; v[6] = (__bf16)f1.z; v[7] = (__bf16)f1.w;
        a[kb] = v;
    }

#pragma unroll
    for (int nb = 0; nb < 4; nb++) {
        f32x4 c = {0.f, 0.f, 0.f, 0.f};
#pragma unroll
        for (int kb = 0; kb < 4; kb++) {
            const bf16x8 b = *(const bf16x8*)(Wo_s + ((size_t)(nb * 4 + kb) * 64 + lane) * 8);
            c = __builtin_amdgcn_mfma_f32_16x16x32_bf16(a[kb], b, c, 0, 0, 0);
        }
        const int col = nb * 16 + m;
        const float bias = bo[col];
#pragma unroll
        for (int r = 0; r < 4; r++) {
            const int node = node0 + q * 4 + r;
            out[(size_t)node * C_OUT + col] = c[r] + bias;
        }
    }
}

extern "C" void kernel_launch(void* const* d_in, const int* in_sizes, int n_in,
                              void* d_out, int out_size, void* d_ws, size_t ws_size,
                              hipStream_t stream) {
    const float* x  = (const float*)d_in[0];
    const int* src  = (const int*)d_in[1];
    const int* dst  = (const int*)d_in[2];
    const float* Wn = (const float*)d_in[3];
    const float* bn = (const float*)d_in[4];
    const float* Wo = (const float*)d_in[5];
    const float* bo = (const float*)d_in[6];

    float* out = (float*)d_out;                  // [N_NODES, 64] final output
    float* emb = out + (size_t)N_NODES * C_OUT;  // [N_NODES, 128] final output
    __bf16* xb = (__bf16*)d_out;                 // bf16 x, aliases `out` region
                                                 // (dead before sage2 writes out)

    int* cnt = (int*)d_ws;                                   // 400 KB
    __bf16* Wn_s = (__bf16*)((char*)d_ws + 400000);          // 32 KB
    __bf16* Wo_s = Wn_s + 128 * 128;                         // 16 KB

    // x -> bf16, zero cnt
    conv_zero<<<(N_NODES * F / 4) / 256, 256, 0, stream>>>(x, xb, (int4*)cnt);

    // bucket edges by destination (bucket inside each node's emb row)
    fill_kernel<<<(N_EDGES + 255) / 256, 256, 0, stream>>>(src, dst, emb, cnt);

    // weights -> bf16 B-fragment layout
    swizzle_kernel<<<12, 256, 0, stream>>>(Wn, Wo, Wn_s, Wo_s);

    // gather + GEMM1 + relu -> emb
    sage1<<<N_NODES / 16, 64, 0, stream>>>(xb, cnt, Wn_s, bn, emb);

    // GEMM2 -> out (xb dead now)
    sage2<<<N_NODES / 16, 64, 0, stream>>>(emb, Wo_s, bo, out);
}

// Round 5
// 219.749 us; speedup vs baseline: 7.2513x; 1.1321x over previous
//
#include <hip/hip_runtime.h>
#include <hip/hip_bf16.h>

#define N_NODES 100000
#define N_EDGES 800000
#define F 128          // IN_FEATS == N_HIDDEN
#define C_OUT 64       // N_CLASSES
#define CAP 48         // per-node bucket capacity (Poisson(8): P(deg>=48)~1e-25)

typedef __bf16 bf16x8 __attribute__((ext_vector_type(8)));
typedef __bf16 bf16x4 __attribute__((ext_vector_type(4)));
typedef __bf16 bf16x2 __attribute__((ext_vector_type(2)));
typedef float f32x4 __attribute__((ext_vector_type(4)));

// ---------------------------------------------------------------------------
// Kernel 1: prep = conv(x->bf16) + edge bucket fill + weight swizzle, fused.
// Grid 3125 x 256 = 800,000 threads exactly (= N_EDGES; N_NODES*F/4 = 4*800k).
//   conv: thread t converts float4 elements {t, t+800k, t+1.6M, t+2.4M}.
//   fill: thread t buckets edge t: slot=cnt[dst]++ (int atomic); bucket for
//         node v = first 48 ints of v's emb row (row-local, consumed by v's
//         own wave in sage1 before being overwritten with emb).
//   swizzle (t<3072): weights -> bf16 B-fragment-linear layout in d_ws.
//         B-frag (mfma 16x16x32_bf16): lane l holds B[k=(l>>4)*8+j][n=l&15].
// cnt must be zeroed before this kernel (hipMemsetAsync).
// ---------------------------------------------------------------------------
__global__ __launch_bounds__(256) void prep(const float* __restrict__ x,
                                            const int* __restrict__ src,
                                            const int* __restrict__ dst,
                                            float* __restrict__ emb,
                                            int* __restrict__ cnt,
                                            const float* __restrict__ Wn,
                                            const float* __restrict__ Wo,
                                            __bf16* __restrict__ Wn_s,
                                            __bf16* __restrict__ Wo_s,
                                            __bf16* __restrict__ xb) {
    const int t = blockIdx.x * 256 + threadIdx.x;

    // ---- conv: 4 strided float4 -> bf16x4 ----
#pragma unroll
    for (int k = 0; k < 4; k++) {
        const int i = k * 800000 + t;
        const float4 v = ((const float4*)x)[i];
        bf16x4 b;
        b.x = (__bf16)v.x; b.y = (__bf16)v.y; b.z = (__bf16)v.z; b.w = (__bf16)v.w;
        *(bf16x4*)(xb + (size_t)i * 4) = b;
    }

    // ---- fill: one edge per thread ----
    const int d = dst[t];
    const int slot = atomicAdd(cnt + d, 1);
    if (slot < CAP) ((int*)(emb + (size_t)d * F))[slot] = src[t];

    // ---- swizzle: 3072 threads total ----
    if (t < 3072) {
        const float* W;
        __bf16* Ws;
        int g, ncols;
        if (t < 2048) { W = Wn; Ws = Wn_s; g = t;        ncols = 128; }
        else          { W = Wo; Ws = Wo_s; g = t - 2048; ncols = 64;  }
        const int l = g & 63;
        const int kb = (g >> 6) & 3;
        const int nb = g >> 8;
        const int q = l >> 4, m = l & 15;
        const int n = nb * 16 + m;
        __bf16 v[8];
#pragma unroll
        for (int j = 0; j < 8; j++) {
            const int k = kb * 32 + q * 8 + j;
            v[j] = (__bf16)W[(size_t)k * ncols + n];
        }
        *(bf16x8*)(Ws + (size_t)g * 8) = *(bf16x8*)v;
    }
}

// 4-edge gather step: bucket int4 -> 4 bf16 row loads (4 B/lane, 256 B/row)
#define ACC4(bk, j, acc)                                                      \
    {                                                                         \
        const int4 s4 = *(const int4*)((bk) + (j));                           \
        const bf16x2 v0 = *(const bf16x2*)(xb + (size_t)s4.x * F + 2 * lane); \
        const bf16x2 v1 = *(const bf16x2*)(xb + (size_t)s4.y * F + 2 * lane); \
        const bf16x2 v2 = *(const bf16x2*)(xb + (size_t)s4.z * F + 2 * lane); \
        const bf16x2 v3 = *(const bf16x2*)(xb + (size_t)s4.w * F + 2 * lane); \
        acc.x += (float)v0.x + (float)v1.x + (float)v2.x + (float)v3.x;       \
        acc.y += (float)v0.y + (float)v1.y + (float)v2.y + (float)v3.y;       \
    }

#define ACC1(bk, j, acc)                                                       \
    {                                                                          \
        const int s = (bk)[j];                                                 \
        const bf16x2 v = *(const bf16x2*)(xb + (size_t)s * F + 2 * lane);      \
        acc.x += (float)v.x;                                                   \
        acc.y += (float)v.y;                                                   \
    }

// ---------------------------------------------------------------------------
// Kernel 2: sage1. 256-thread blocks = 4 INDEPENDENT waves (no barriers),
// each wave owns 16 nodes + its own LDS slice:
//   gather (2-node interleave, 8 loads in flight) -> h bf16 in LDS
//   -> MFMA GEMM1 -> relu -> LDS f32 transpose -> coalesced float4 emb stores.
// LDS 4*4352B = 17.4KB/block -> 8 blocks/CU; launch_bounds(256,8) caps VGPR
// at 64 -> up to 32 waves/CU (vs 29% occupancy with 1-wave blocks in R4).
// A-frag: lane holds A[m=lane&15][k=(lane>>4)*8+j]; C/D: row=(lane>>4)*4+r,
// col=lane&15 (m89-verified).
// ---------------------------------------------------------------------------
__global__ __launch_bounds__(256, 8) void sage1(const __bf16* __restrict__ xb,
                                                const int* __restrict__ cnt,
                                                const __bf16* __restrict__ Wn_s,
                                                const float* __restrict__ bn,
                                                float* emb) {
    __shared__ __align__(16) __bf16 Hs[4][16][136];  // 4352 B per wave
    const int w = threadIdx.x >> 6;
    const int lane = threadIdx.x & 63;
    const int node0 = (blockIdx.x * 4 + w) * 16;
    if (node0 >= N_NODES) return;  // 1563 blocks * 4 waves = 6252; 2 idle
    const int q = lane >> 4, m = lane & 15;
    __bf16(*H)[136] = Hs[w];

    // ---- gather: h[v] = (sum_{u->v} xb[u] + xb[v]) / (deg+1) ----
    for (int i = 0; i < 16; i += 2) {
        const int nodeA = node0 + i, nodeB = nodeA + 1;
        const int degA = cnt[nodeA], degB = cnt[nodeB];
        const int nA = degA < CAP ? degA : CAP;
        const int nB = degB < CAP ? degB : CAP;
        const bf16x2 sA = *(const bf16x2*)(xb + (size_t)nodeA * F + 2 * lane);
        const bf16x2 sB = *(const bf16x2*)(xb + (size_t)nodeB * F + 2 * lane);
        float2 accA = make_float2((float)sA.x, (float)sA.y);
        float2 accB = make_float2((float)sB.x, (float)sB.y);
        const int* bkA = (const int*)(emb + (size_t)nodeA * F);
        const int* bkB = (const int*)(emb + (size_t)nodeB * F);
        int ja = 0, jb = 0;
        while ((ja + 4 <= nA) && (jb + 4 <= nB)) {  // 8 row loads in flight
            ACC4(bkA, ja, accA);
            ACC4(bkB, jb, accB);
            ja += 4; jb += 4;
        }
        while (ja + 4 <= nA) { ACC4(bkA, ja, accA); ja += 4; }
        while (jb + 4 <= nB) { ACC4(bkB, jb, accB); jb += 4; }
        while ((ja < nA) && (jb < nB)) { ACC1(bkA, ja, accA); ACC1(bkB, jb, accB); ja++; jb++; }
        while (ja < nA) { ACC1(bkA, ja, accA); ja++; }
        while (jb < nB) { ACC1(bkB, jb, accB); jb++; }

        const float invA = 1.0f / (float)(degA + 1);
        const float invB = 1.0f / (float)(degB + 1);
        bf16x2 hA, hB;
        hA.x = (__bf16)(accA.x * invA); hA.y = (__bf16)(accA.y * invA);
        hB.x = (__bf16)(accB.x * invB); hB.y = (__bf16)(accB.y * invB);
        *(bf16x2*)&H[i][2 * lane] = hA;
        *(bf16x2*)&H[i + 1][2 * lane] = hB;
    }

    // ---- A-fragments (after this, H is dead and reused as f32 scratch) ----
    bf16x8 a[4];
#pragma unroll
    for (int kb = 0; kb < 4; kb++)
        a[kb] = *(const bf16x8*)&H[m][kb * 32 + q * 8];
    asm volatile("s_waitcnt lgkmcnt(0)" ::: "memory");  // a[] landed; H reusable

    // ---- GEMM1 + relu + LDS f32 transpose + coalesced emb stores ----
    // Ef overlays H: [16][68] f32 = 4352 B exactly; both access directions are
    // 2-way bank aliased (free on CDNA4, m136).
    float* Ef = (float*)&H[0][0];
    const int srow = lane >> 2;            // store row 0..15
    const int sc4 = (lane & 3) * 4;        // store col group
#pragma unroll
    for (int half = 0; half < 2; half++) {
#pragma unroll
        for (int nb2 = 0; nb2 < 4; nb2++) {
            const int nb = half * 4 + nb2;
            f32x4 c = {0.f, 0.f, 0.f, 0.f};
#pragma unroll
            for (int kb = 0; kb < 4; kb++) {
                const bf16x8 b = *(const bf16x8*)(Wn_s + ((size_t)(nb * 4 + kb) * 64 + lane) * 8);
                c = __builtin_amdgcn_mfma_f32_16x16x32_bf16(a[kb], b, c, 0, 0, 0);
            }
            const float bias = bn[nb * 16 + m];
#pragma unroll
            for (int r = 0; r < 4; r++)
                Ef[(q * 4 + r) * 68 + nb2 * 16 + m] = fmaxf(c[r] + bias, 0.f);
        }
        asm volatile("s_waitcnt lgkmcnt(0)" ::: "memory");  // transpose visible
#pragma unroll
        for (int it = 0; it < 4; it++) {
            const f32x4 v = *(const f32x4*)&Ef[srow * 68 + it * 16 + sc4];
            *(f32x4*)&emb[(size_t)(node0 + srow) * F + half * 64 + it * 16 + sc4] = v;
        }
        if (half == 0) asm volatile("s_waitcnt lgkmcnt(0)" ::: "memory");  // reads done before overwrite
    }
}

// ---------------------------------------------------------------------------
// Kernel 3: sage2: out = emb @ Wo + bo. 4 independent waves per block, one
// wave per 16 nodes; A-frags from global emb (fp32 -> bf16 in-register).
// Runs after sage1, so xb (out region) is dead.
// ---------------------------------------------------------------------------
__global__ __launch_bounds__(256, 6) void sage2(const float* __restrict__ emb,
                                                const __bf16* __restrict__ Wo_s,
                                                const float* __restrict__ bo,
                                                float* __restrict__ out) {
    const int w = threadIdx.x >> 6;
    const int lane = threadIdx.x & 63;
    const int node0 = (blockIdx.x * 4 + w) * 16;
    if (node0 >= N_NODES) return;
    const int q = lane >> 4, m = lane & 15;

    bf16x8 a[4];
#pragma unroll
    for (int kb = 0; kb < 4; kb++) {
        const float* p = emb + (size_t)(node0 + m) * F + kb * 32 + q * 8;
        const float4 f0 = *(const float4*)(p);
        const float4 f1 = *(const float4*)(p + 4);
        bf16x8 v;
        v[0] = (__bf16)f0.x; v[1] = (__bf16)f0.y; v[2] = (__bf16)f0.z; v[3] = (__bf16)f0.w;
        v[4] = (__bf16)f1.x; v[5] = (__bf16)f1.y; v[6] = (__bf16)f1.z; v[7] = (__bf16)f1.w;
        a[kb] = v;
    }

#pragma unroll
    for (int nb = 0; nb < 4; nb++) {
        f32x4 c = {0.f, 0.f, 0.f, 0.f};
#pragma unroll
        for (int kb = 0; kb < 4; kb++) {
            const bf16x8 b = *(const bf16x8*)(Wo_s + ((size_t)(nb * 4 + kb) * 64 + lane) * 8);
            c = __builtin_amdgcn_mfma_f32_16x16x32_bf16(a[kb], b, c, 0, 0, 0);
        }
        const int col = nb * 16 + m;
        const float bias = bo[col];
#pragma unroll
        for (int r = 0; r < 4; r++) {
            const int node = node0 + q * 4 + r;
            out[(size_t)node * C_OUT + col] = c[r] + bias;
        }
    }
}

extern "C" void kernel_launch(void* const* d_in, const int* in_sizes, int n_in,
                              void* d_out, int out_size, void* d_ws, size_t ws_size,
                              hipStream_t stream) {
    const float* x  = (const float*)d_in[0];
    const int* src  = (const int*)d_in[1];
    const int* dst  = (const int*)d_in[2];
    const float* Wn = (const float*)d_in[3];
    const float* bn = (const float*)d_in[4];
    const float* Wo = (const float*)d_in[5];
    const float* bo = (const float*)d_in[6];

    float* out = (float*)d_out;                  // [N_NODES, 64] final output
    float* emb = out + (size_t)N_NODES * C_OUT;  // [N_NODES, 128] final output
    __bf16* xb = (__bf16*)d_out;                 // bf16 x, aliases `out` region
                                                 // (dead before sage2 writes out)

    int* cnt = (int*)d_ws;                                   // 400 KB
    __bf16* Wn_s = (__bf16*)((char*)d_ws + 400000);          // 32 KB
    __bf16* Wo_s = Wn_s + 128 * 128;                         // 16 KB

    hipMemsetAsync(cnt, 0, N_NODES * sizeof(int), stream);

    // conv + fill + swizzle fused (3125*256 = 800,000 threads exact)
    prep<<<3125, 256, 0, stream>>>(x, src, dst, emb, cnt, Wn, Wo, Wn_s, Wo_s, xb);

    // gather + GEMM1 + relu -> emb
    sage1<<<(N_NODES + 63) / 64, 256, 0, stream>>>(xb, cnt, Wn_s, bn, emb);

    // GEMM2 -> out (xb dead now)
    sage2<<<(N_NODES + 63) / 64, 256, 0, stream>>>(emb, Wo_s, bo, out);
}

// Round 6
// 215.169 us; speedup vs baseline: 7.4057x; 1.0213x over previous
//
#include <hip/hip_runtime.h>
#include <hip/hip_bf16.h>

#define N_NODES 100000
#define N_EDGES 800000
#define F 128          // IN_FEATS == N_HIDDEN
#define C_OUT 64       // N_CLASSES
#define CAP 48         // per-node bucket capacity (Poisson(8): P(deg>=48)~1e-25)
#define DUMMY N_NODES  // dummy src index -> zero row appended to xb (ws path)

typedef __bf16 bf16x8 __attribute__((ext_vector_type(8)));
typedef __bf16 bf16x4 __attribute__((ext_vector_type(4)));
typedef __bf16 bf16x2 __attribute__((ext_vector_type(2)));
typedef float f32x4 __attribute__((ext_vector_type(4)));

// ---------------------------------------------------------------------------
// prep = conv(x->bf16) + edge bucket fill + weight swizzle (+ zero dummy row).
// Grid 3125 x 256 = 800,000 threads exactly.
// ---------------------------------------------------------------------------
__global__ __launch_bounds__(256) void prep(const float* __restrict__ x,
                                            const int* __restrict__ src,
                                            const int* __restrict__ dst,
                                            float* __restrict__ emb,
                                            int* __restrict__ cnt,
                                            const float* __restrict__ Wn,
                                            const float* __restrict__ Wo,
                                            __bf16* __restrict__ Wn_s,
                                            __bf16* __restrict__ Wo_s,
                                            __bf16* __restrict__ xb,
                                            int zero_dummy) {
    const int t = blockIdx.x * 256 + threadIdx.x;

    // ---- conv: 4 strided float4 -> bf16x4 ----
#pragma unroll
    for (int k = 0; k < 4; k++) {
        const int i = k * 800000 + t;
        const float4 v = ((const float4*)x)[i];
        bf16x4 b;
        b.x = (__bf16)v.x; b.y = (__bf16)v.y; b.z = (__bf16)v.z; b.w = (__bf16)v.w;
        *(bf16x4*)(xb + (size_t)i * 4) = b;
    }

    // ---- zero dummy row (row N_NODES, 256 B) for gather padding ----
    if (zero_dummy && t < 32) {
        int2 z = make_int2(0, 0);
        ((int2*)(xb + (size_t)N_NODES * F))[t] = z;
    }

    // ---- fill: one edge per thread; bucket = first 48 ints of dst's emb row
    const int d = dst[t];
    const int slot = atomicAdd(cnt + d, 1);
    if (slot < CAP) ((int*)(emb + (size_t)d * F))[slot] = src[t];

    // ---- swizzle: weights -> bf16 B-fragment-linear (lane l holds
    //      B[k=(l>>4)*8+j][n=l&15]); group g=(nb*4+kb)*64+lane ----
    if (t < 3072) {
        const float* W;
        __bf16* Ws;
        int g, ncols;
        if (t < 2048) { W = Wn; Ws = Wn_s; g = t;        ncols = 128; }
        else          { W = Wo; Ws = Wo_s; g = t - 2048; ncols = 64;  }
        const int l = g & 63;
        const int kb = (g >> 6) & 3;
        const int nb = g >> 8;
        const int q = l >> 4, m = l & 15;
        const int n = nb * 16 + m;
        __bf16 v[8];
#pragma unroll
        for (int j = 0; j < 8; j++) {
            const int k = kb * 32 + q * 8 + j;
            v[j] = (__bf16)W[(size_t)k * ncols + n];
        }
        *(bf16x8*)(Ws + (size_t)g * 8) = *(bf16x8*)v;
    }
}

// 4-edge gather step: bucket int4 -> 4 bf16 row loads (4 B/lane, 256 B/row)
#define ACC4(bk, j, acc)                                                      \
    {                                                                         \
        const int4 s4 = *(const int4*)((bk) + (j));                           \
        const bf16x2 v0 = *(const bf16x2*)(xb + (size_t)s4.x * F + 2 * lane); \
        const bf16x2 v1 = *(const bf16x2*)(xb + (size_t)s4.y * F + 2 * lane); \
        const bf16x2 v2 = *(const bf16x2*)(xb + (size_t)s4.z * F + 2 * lane); \
        const bf16x2 v3 = *(const bf16x2*)(xb + (size_t)s4.w * F + 2 * lane); \
        acc.x += (float)v0.x + (float)v1.x + (float)v2.x + (float)v3.x;       \
        acc.y += (float)v0.y + (float)v1.y + (float)v2.y + (float)v3.y;       \
    }

#define ACC1(bk, j, acc)                                                       \
    {                                                                          \
        const int s = (bk)[j];                                                 \
        const bf16x2 v = *(const bf16x2*)(xb + (size_t)s * F + 2 * lane);      \
        acc.x += (float)v.x;                                                   \
        acc.y += (float)v.y;                                                   \
    }

// ---------------------------------------------------------------------------
// sage_fused (ws path): 4 independent waves/block, 16 nodes/wave, no barriers.
//   gather (4-node interleave, dummy-padded to x4 -> 4 int4 + 16 row loads in
//   flight) -> h bf16 LDS -> MFMA GEMM1 -> relu -> f32 LDS transpose ->
//   coalesced emb stores + A2-frags re-read from same LDS (per-half partial
//   K-accumulation) -> MFMA GEMM2 -> coalesced out stores.
// A-frag: lane holds A[m=lane&15][k=(lane>>4)*8+j]; C/D: row=(lane>>4)*4+r,
// col=lane&15 (m89-verified).
// ---------------------------------------------------------------------------
__global__ __launch_bounds__(256, 6) void sage_fused(const __bf16* __restrict__ xb,
                                                     const int* __restrict__ cnt,
                                                     const __bf16* __restrict__ Wn_s,
                                                     const __bf16* __restrict__ Wo_s,
                                                     const float* __restrict__ bn,
                                                     const float* __restrict__ bo,
                                                     float* __restrict__ out,
                                                     float* emb) {
    __shared__ __align__(16) __bf16 Hs[4][16][136];  // 4352 B per wave
    const int w = threadIdx.x >> 6;
    const int lane = threadIdx.x & 63;
    const int node0 = (blockIdx.x * 4 + w) * 16;
    if (node0 >= N_NODES) return;  // 1563*4 = 6252 waves; 2 idle
    const int q = lane >> 4, m = lane & 15;
    __bf16(*H)[136] = Hs[w];

    // ---- gather: groups of 4 nodes, buckets padded to multiple of 4 ----
    for (int i = 0; i < 16; i += 4) {
        const int na = node0 + i;
        const int4 dg = *(const int4*)(cnt + na);  // na % 4 == 0, aligned
        const int n0 = dg.x < CAP ? dg.x : CAP, n1 = dg.y < CAP ? dg.y : CAP;
        const int n2 = dg.z < CAP ? dg.z : CAP, n3 = dg.w < CAP ? dg.w : CAP;
        const int p0 = (n0 + 3) & ~3, p1 = (n1 + 3) & ~3;
        const int p2 = (n2 + 3) & ~3, p3 = (n3 + 3) & ~3;
        const int* bk0 = (const int*)(emb + (size_t)(na + 0) * F);
        const int* bk1 = (const int*)(emb + (size_t)(na + 1) * F);
        const int* bk2 = (const int*)(emb + (size_t)(na + 2) * F);
        const int* bk3 = (const int*)(emb + (size_t)(na + 3) * F);
        // self terms (also fill load queue)
        const bf16x2 s0 = *(const bf16x2*)(xb + (size_t)(na + 0) * F + 2 * lane);
        const bf16x2 s1 = *(const bf16x2*)(xb + (size_t)(na + 1) * F + 2 * lane);
        const bf16x2 s2 = *(const bf16x2*)(xb + (size_t)(na + 2) * F + 2 * lane);
        const bf16x2 s3 = *(const bf16x2*)(xb + (size_t)(na + 3) * F + 2 * lane);
        // pad slots [n, p) with DUMMY (zero row): lanes 0..3, <=3 writes each
        if (lane < 4) {
            const int nn = lane == 0 ? n0 : lane == 1 ? n1 : lane == 2 ? n2 : n3;
            const int pp = lane == 0 ? p0 : lane == 1 ? p1 : lane == 2 ? p2 : p3;
            int* bw = (int*)(lane == 0 ? bk0 : lane == 1 ? bk1 : lane == 2 ? bk2 : bk3);
            for (int s = nn; s < pp; s++) bw[s] = DUMMY;
        }
        asm volatile("s_waitcnt vmcnt(0)" ::: "memory");  // pads visible to wave

        float2 a0 = make_float2((float)s0.x, (float)s0.y);
        float2 a1 = make_float2((float)s1.x, (float)s1.y);
        float2 a2 = make_float2((float)s2.x, (float)s2.y);
        float2 a3 = make_float2((float)s3.x, (float)s3.y);
        const int jmax = max(max(p0, p1), max(p2, p3));
        for (int j = 0; j < jmax; j += 4) {  // up to 16 row loads in flight
            if (j < p0) ACC4(bk0, j, a0);
            if (j < p1) ACC4(bk1, j, a1);
            if (j < p2) ACC4(bk2, j, a2);
            if (j < p3) ACC4(bk3, j, a3);
        }
        const float i0 = 1.0f / (float)(dg.x + 1), i1 = 1.0f / (float)(dg.y + 1);
        const float i2 = 1.0f / (float)(dg.z + 1), i3 = 1.0f / (float)(dg.w + 1);
        bf16x2 h0, h1, h2, h3;
        h0.x = (__bf16)(a0.x * i0); h0.y = (__bf16)(a0.y * i0);
        h1.x = (__bf16)(a1.x * i1); h1.y = (__bf16)(a1.y * i1);
        h2.x = (__bf16)(a2.x * i2); h2.y = (__bf16)(a2.y * i2);
        h3.x = (__bf16)(a3.x * i3); h3.y = (__bf16)(a3.y * i3);
        *(bf16x2*)&H[i + 0][2 * lane] = h0;
        *(bf16x2*)&H[i + 1][2 * lane] = h1;
        *(bf16x2*)&H[i + 2][2 * lane] = h2;
        *(bf16x2*)&H[i + 3][2 * lane] = h3;
    }

    // ---- A-fragments; H then reused as f32 [16][68] scratch ----
    bf16x8 afr[4];
#pragma unroll
    for (int kb = 0; kb < 4; kb++)
        afr[kb] = *(const bf16x8*)&H[m][kb * 32 + q * 8];
    asm volatile("s_waitcnt lgkmcnt(0)" ::: "memory");

    float* Ef = (float*)&H[0][0];
    const int srow = lane >> 2;       // store row 0..15
    const int sc4 = (lane & 3) * 4;   // store col group
    f32x4 o[4];
#pragma unroll
    for (int nb = 0; nb < 4; nb++) o[nb] = (f32x4){0.f, 0.f, 0.f, 0.f};

#pragma unroll
    for (int half = 0; half < 2; half++) {
        // GEMM1 for this half's 64 emb cols + relu -> LDS f32 transpose
#pragma unroll
        for (int nb2 = 0; nb2 < 4; nb2++) {
            const int nb = half * 4 + nb2;
            f32x4 c = {0.f, 0.f, 0.f, 0.f};
#pragma unroll
            for (int kb = 0; kb < 4; kb++) {
                const bf16x8 b = *(const bf16x8*)(Wn_s + ((size_t)(nb * 4 + kb) * 64 + lane) * 8);
                c = __builtin_amdgcn_mfma_f32_16x16x32_bf16(afr[kb], b, c, 0, 0, 0);
            }
            const float bias = bn[nb * 16 + m];
#pragma unroll
            for (int r = 0; r < 4; r++)
                Ef[(q * 4 + r) * 68 + nb2 * 16 + m] = fmaxf(c[r] + bias, 0.f);
        }
        asm volatile("s_waitcnt lgkmcnt(0)" ::: "memory");  // transpose visible
        // coalesced emb stores (float4, 64 B runs)
#pragma unroll
        for (int it = 0; it < 4; it++) {
            const f32x4 v = *(const f32x4*)&Ef[srow * 68 + it * 16 + sc4];
            *(f32x4*)&emb[(size_t)(node0 + srow) * F + half * 64 + it * 16 + sc4] = v;
        }
        // GEMM2 partial accumulation over this half's 2 k-blocks
#pragma unroll
        for (int t2 = 0; t2 < 2; t2++) {
            const int kb = half * 2 + t2;
            const f32x4 f0 = *(const f32x4*)&Ef[m * 68 + t2 * 32 + q * 8];
            const f32x4 f1 = *(const f32x4*)&Ef[m * 68 + t2 * 32 + q * 8 + 4];
            bf16x8 a2f;
            a2f[0] = (__bf16)f0[0]; a2f[1] = (__bf16)f0[1];
            a2f[2] = (__bf16)f0[2]; a2f[3] = (__bf16)f0[3];
            a2f[4] = (__bf16)f1[0]; a2f[5] = (__bf16)f1[1];
            a2f[6] = (__bf16)f1[2]; a2f[7] = (__bf16)f1[3];
#pragma unroll
            for (int nb = 0; nb < 4; nb++) {
                const bf16x8 b = *(const bf16x8*)(Wo_s + ((size_t)(nb * 4 + kb) * 64 + lane) * 8);
                o[nb] = __builtin_amdgcn_mfma_f32_16x16x32_bf16(a2f, b, o[nb], 0, 0, 0);
            }
        }
        asm volatile("s_waitcnt lgkmcnt(0)" ::: "memory");  // reads done before overwrite
    }

    // ---- out epilogue: bias -> LDS f32 transpose -> coalesced stores ----
#pragma unroll
    for (int nb = 0; nb < 4; nb++) {
        const float bias = bo[nb * 16 + m];
#pragma unroll
        for (int r = 0; r < 4; r++)
            Ef[(q * 4 + r) * 68 + nb * 16 + m] = o[nb][r] + bias;
    }
    asm volatile("s_waitcnt lgkmcnt(0)" ::: "memory");
#pragma unroll
    for (int it = 0; it < 4; it++) {
        const f32x4 v = *(const f32x4*)&Ef[srow * 68 + it * 16 + sc4];
        *(f32x4*)&out[(size_t)(node0 + srow) * C_OUT + it * 16 + sc4] = v;
    }
}

// ---------------------------------------------------------------------------
// Fallback path (ws too small for xb): R5's proven two-kernel structure with
// xb aliased over the `out` region (dead before sage2 writes out).
// ---------------------------------------------------------------------------
__global__ __launch_bounds__(256, 8) void sage1_fb(const __bf16* __restrict__ xb,
                                                   const int* __restrict__ cnt,
                                                   const __bf16* __restrict__ Wn_s,
                                                   const float* __restrict__ bn,
                                                   float* emb) {
    __shared__ __align__(16) __bf16 Hs[4][16][136];
    const int w = threadIdx.x >> 6;
    const int lane = threadIdx.x & 63;
    const int node0 = (blockIdx.x * 4 + w) * 16;
    if (node0 >= N_NODES) return;
    const int q = lane >> 4, m = lane & 15;
    __bf16(*H)[136] = Hs[w];

    for (int i = 0; i < 16; i += 2) {
        const int nodeA = node0 + i, nodeB = nodeA + 1;
        const int degA = cnt[nodeA], degB = cnt[nodeB];
        const int nA = degA < CAP ? degA : CAP;
        const int nB = degB < CAP ? degB : CAP;
        const bf16x2 sA = *(const bf16x2*)(xb + (size_t)nodeA * F + 2 * lane);
        const bf16x2 sB = *(const bf16x2*)(xb + (size_t)nodeB * F + 2 * lane);
        float2 accA = make_float2((float)sA.x, (float)sA.y);
        float2 accB = make_float2((float)sB.x, (float)sB.y);
        const int* bkA = (const int*)(emb + (size_t)nodeA * F);
        const int* bkB = (const int*)(emb + (size_t)nodeB * F);
        int ja = 0, jb = 0;
        while ((ja + 4 <= nA) && (jb + 4 <= nB)) {
            ACC4(bkA, ja, accA);
            ACC4(bkB, jb, accB);
            ja += 4; jb += 4;
        }
        while (ja + 4 <= nA) { ACC4(bkA, ja, accA); ja += 4; }
        while (jb + 4 <= nB) { ACC4(bkB, jb, accB); jb += 4; }
        while ((ja < nA) && (jb < nB)) { ACC1(bkA, ja, accA); ACC1(bkB, jb, accB); ja++; jb++; }
        while (ja < nA) { ACC1(bkA, ja, accA); ja++; }
        while (jb < nB) { ACC1(bkB, jb, accB); jb++; }
        const float invA = 1.0f / (float)(degA + 1);
        const float invB = 1.0f / (float)(degB + 1);
        bf16x2 hA, hB;
        hA.x = (__bf16)(accA.x * invA); hA.y = (__bf16)(accA.y * invA);
        hB.x = (__bf16)(accB.x * invB); hB.y = (__bf16)(accB.y * invB);
        *(bf16x2*)&H[i][2 * lane] = hA;
        *(bf16x2*)&H[i + 1][2 * lane] = hB;
    }

    bf16x8 a[4];
#pragma unroll
    for (int kb = 0; kb < 4; kb++)
        a[kb] = *(const bf16x8*)&H[m][kb * 32 + q * 8];
    asm volatile("s_waitcnt lgkmcnt(0)" ::: "memory");

    float* Ef = (float*)&H[0][0];
    const int srow = lane >> 2;
    const int sc4 = (lane & 3) * 4;
#pragma unroll
    for (int half = 0; half < 2; half++) {
#pragma unroll
        for (int nb2 = 0; nb2 < 4; nb2++) {
            const int nb = half * 4 + nb2;
            f32x4 c = {0.f, 0.f, 0.f, 0.f};
#pragma unroll
            for (int kb = 0; kb < 4; kb++) {
                const bf16x8 b = *(const bf16x8*)(Wn_s + ((size_t)(nb * 4 + kb) * 64 + lane) * 8);
                c = __builtin_amdgcn_mfma_f32_16x16x32_bf16(a[kb], b, c, 0, 0, 0);
            }
            const float bias = bn[nb * 16 + m];
#pragma unroll
            for (int r = 0; r < 4; r++)
                Ef[(q * 4 + r) * 68 + nb2 * 16 + m] = fmaxf(c[r] + bias, 0.f);
        }
        asm volatile("s_waitcnt lgkmcnt(0)" ::: "memory");
#pragma unroll
        for (int it = 0; it < 4; it++) {
            const f32x4 v = *(const f32x4*)&Ef[srow * 68 + it * 16 + sc4];
            *(f32x4*)&emb[(size_t)(node0 + srow) * F + half * 64 + it * 16 + sc4] = v;
        }
        if (half == 0) asm volatile("s_waitcnt lgkmcnt(0)" ::: "memory");
    }
}

__global__ __launch_bounds__(256, 6) void sage2_fb(const float* __restrict__ emb,
                                                   const __bf16* __restrict__ Wo_s,
                                                   const float* __restrict__ bo,
                                                   float* __restrict__ out) {
    const int w = threadIdx.x >> 6;
    const int lane = threadIdx.x & 63;
    const int node0 = (blockIdx.x * 4 + w) * 16;
    if (node0 >= N_NODES) return;
    const int q = lane >> 4, m = lane & 15;

    bf16x8 a[4];
#pragma unroll
    for (int kb = 0; kb < 4; kb++) {
        const float* p = emb + (size_t)(node0 + m) * F + kb * 32 + q * 8;
        const float4 f0 = *(const float4*)(p);
        const float4 f1 = *(const float4*)(p + 4);
        bf16x8 v;
        v[0] = (__bf16)f0.x; v[1] = (__bf16)f0.y; v[2] = (__bf16)f0.z; v[3] = (__bf16)f0.w;
        v[4] = (__bf16)f1.x; v[5] = (__bf16)f1.y; v[6] = (__bf16)f1.z; v[7] = (__bf16)f1.w;
        a[kb] = v;
    }
#pragma unroll
    for (int nb = 0; nb < 4; nb++) {
        f32x4 c = {0.f, 0.f, 0.f, 0.f};
#pragma unroll
        for (int kb = 0; kb < 4; kb++) {
            const bf16x8 b = *(const bf16x8*)(Wo_s + ((size_t)(nb * 4 + kb) * 64 + lane) * 8);
            c = __builtin_amdgcn_mfma_f32_16x16x32_bf16(a[kb], b, c, 0, 0, 0);
        }
        const int col = nb * 16 + m;
        const float bias = bo[col];
#pragma unroll
        for (int r = 0; r < 4; r++) {
            const int node = node0 + q * 4 + r;
            out[(size_t)node * C_OUT + col] = c[r] + bias;
        }
    }
}

extern "C" void kernel_launch(void* const* d_in, const int* in_sizes, int n_in,
                              void* d_out, int out_size, void* d_ws, size_t ws_size,
                              hipStream_t stream) {
    const float* x  = (const float*)d_in[0];
    const int* src  = (const int*)d_in[1];
    const int* dst  = (const int*)d_in[2];
    const float* Wn = (const float*)d_in[3];
    const float* bn = (const float*)d_in[4];
    const float* Wo = (const float*)d_in[5];
    const float* bo = (const float*)d_in[6];

    float* out = (float*)d_out;                  // [N_NODES, 64] final output
    float* emb = out + (size_t)N_NODES * C_OUT;  // [N_NODES, 128] final output

    int* cnt = (int*)d_ws;                                   // 400,000 B
    __bf16* Wn_s = (__bf16*)((char*)d_ws + 400000);          // 32,768 B
    __bf16* Wo_s = Wn_s + 128 * 128;                         // 16,384 B
    __bf16* xb_ws = (__bf16*)((char*)d_ws + 449152);         // 100001 rows bf16

    const size_t WS_NEEDED = 449152 + (size_t)(N_NODES + 1) * F * 2;  // ~26.05 MB
    const bool fused = ws_size >= WS_NEEDED;  // constant across calls: graph-safe

    hipMemsetAsync(cnt, 0, N_NODES * sizeof(int), stream);

    if (fused) {
        prep<<<3125, 256, 0, stream>>>(x, src, dst, emb, cnt, Wn, Wo, Wn_s, Wo_s,
                                       xb_ws, 1);
        sage_fused<<<(N_NODES + 63) / 64, 256, 0, stream>>>(xb_ws, cnt, Wn_s, Wo_s,
                                                            bn, bo, out, emb);
    } else {
        __bf16* xb = (__bf16*)d_out;  // aliases `out` region (dead before sage2)
        prep<<<3125, 256, 0, stream>>>(x, src, dst, emb, cnt, Wn, Wo, Wn_s, Wo_s,
                                       xb, 0);
        sage1_fb<<<(N_NODES + 63) / 64, 256, 0, stream>>>(xb, cnt, Wn_s, bn, emb);
        sage2_fb<<<(N_NODES + 63) / 64, 256, 0, stream>>>(emb, Wo_s, bo, out);
    }
}